// Round 1
// baseline (2660.666 us; speedup 1.0000x reference)
//
#include <hip/hip_runtime.h>

// Problem constants (from reference)
#define NCC 1024      // cells
#define HSZ 256       // state/msg hidden
#define HMODL 128     // mod hidden
#define MODIN 198
#define MODOUT 68

__device__ __forceinline__ float fast_tanh(float x) {
    x = fminf(15.f, fmaxf(-15.f, x));
    float e = __expf(2.f * x);
    return (e - 1.f) / (e + 1.f);
}
__device__ __forceinline__ float fast_sigmoid(float x) {
    x = fminf(30.f, fmaxf(-30.f, x));
    return 1.f / (1.f + __expf(-x));
}
__device__ __forceinline__ void fma4(float& acc, const float4 a, const float4 b) {
    acc = fmaf(a.x, b.x, acc);
    acc = fmaf(a.y, b.y, acc);
    acc = fmaf(a.z, b.z, acc);
    acc = fmaf(a.w, b.w, acc);
}

// ---------------------------------------------------------------------------
// Kernel 1: per (b, cell) block. Stages 1-6 + feats assembly.
//   block = 256 threads (4 waves), grid = BS*NC = 8192
// ---------------------------------------------------------------------------
__global__ __launch_bounds__(256, 1)
void mg_cell_kernel(
    const float* __restrict__ xp,   const float* __restrict__ hp,
    const float* __restrict__ msgp, const float* __restrict__ Wp,
    const float* __restrict__ decayp, const float* __restrict__ ctxp,
    const float* __restrict__ bglp, const float* __restrict__ nidp,
    const float* __restrict__ sw1,  const float* __restrict__ sb1,
    const float* __restrict__ sgs1, const float* __restrict__ sgb1,
    const float* __restrict__ sw2,  const float* __restrict__ sb2,
    const float* __restrict__ sgs2, const float* __restrict__ sgb2,
    const float* __restrict__ mw1,  const float* __restrict__ mb1,
    const float* __restrict__ mgs1, const float* __restrict__ mgb1,
    const float* __restrict__ mw2,  const float* __restrict__ mb2,
    const float* __restrict__ mgs2, const float* __restrict__ mgb2,
    const float* __restrict__ iw,   const float* __restrict__ ibias,
    const int*   __restrict__ c2g,
    float* __restrict__ out_read, float* __restrict__ out_h,
    float* __restrict__ out_msg,  float* __restrict__ feats)
{
    const int t    = threadIdx.x;
    const int bc   = blockIdx.x;
    const int b    = bc >> 10;
    const int c    = bc & 1023;
    const int gh   = c >> 5, gwcol = c & 31;
    const int lane = t & 63, w = t >> 6;
    const int g    = c2g[c];

    // s_in[n][0:64] = received (later h_new); s_in[n][64:128] = h
    __shared__ __align__(16) float s_in[64][132];
    __shared__ __align__(16) float s_hid[64][260];
    __shared__ __align__(16) float s_x[64];
    __shared__ float s_inj[256];
    __shared__ float s_inc[4][64];
    __shared__ float s_hmean[64];
    __shared__ float s_mmean[64];
    __shared__ float s_red[2];   // [0] = sum|W| (x4), [1] = sum decay_logit

    const size_t tile = (size_t)bc * 4096;
    const float* Wt = Wp + tile;
    const float* Mt = msgp + tile;
    const float* Ht = hp + tile;

    // ---- P0: zero reductions, load x slice, gated border incoming, h -> LDS,
    //          decay_logit sum (wave 0)
    if (t < 64) { s_hmean[t] = 0.f; s_mmean[t] = 0.f; }
    if (t == 0) s_red[0] = 0.f;
    if (t < 16)
        *(float4*)&s_x[t * 4] = *(const float4*)&xp[((size_t)b * NCC + c) * 64 + t * 4];
    {
        const int p = w, d = lane;
        int ok, nc2, q;
        if      (p == 0) { ok = (gh > 0);     nc2 = c - 32; q = 1; }
        else if (p == 1) { ok = (gh < 31);    nc2 = c + 32; q = 0; }
        else if (p == 2) { ok = (gwcol > 0);  nc2 = c - 1;  q = 3; }
        else             { ok = (gwcol < 31); nc2 = c + 1;  q = 2; }
        float v = 0.f;
        if (ok) v = msgp[((size_t)b * NCC + nc2) * 4096 + (8 + q) * 64 + d];
        const float gate = fast_sigmoid(bglp[(size_t)bc * 4 + p]);
        s_inc[p][d] = gate * v;
    }
    for (int k = t; k < 1024; k += 256) {
        const int e = k * 4;
        *(float4*)&s_in[e >> 6][64 + (e & 63)] = *(const float4*)&Ht[e];
    }
    if (w == 0) {
        float v = decayp[(size_t)bc * 64 + lane];
        #pragma unroll
        for (int off = 32; off > 0; off >>= 1) v += __shfl_down(v, off);
        if (lane == 0) s_red[1] = v;
    }
    __syncthreads();

    // ---- P1: inject (o = t) and W @ msg (thread = (n = t>>2, d-quarter = t&3))
    {
        const float* iwg = iw + (size_t)g * (256 * 64);
        float accv = 0.f;
        for (int i = 0; i < 64; i += 4) {
            const float4 w4 = *(const float4*)&iwg[t * 64 + i];
            const float4 x4 = *(const float4*)&s_x[i];
            fma4(accv, w4, x4);
        }
        s_inj[t] = accv + ibias[(size_t)g * 256 + t];
    }
    const int an = t >> 2, ad0 = (t & 3) * 16;
    float racc[16];
    #pragma unroll
    for (int j = 0; j < 16; j++) racc[j] = 0.f;
    {
        float wsum = 0.f;
        for (int mc = 0; mc < 64; mc += 4) {
            const float4 w4 = *(const float4*)&Wt[an * 64 + mc];
            wsum += fabsf(w4.x) + fabsf(w4.y) + fabsf(w4.z) + fabsf(w4.w);
            const float wk[4] = {w4.x, w4.y, w4.z, w4.w};
            #pragma unroll
            for (int k = 0; k < 4; k++) {
                const float wv = wk[k];
                const float* mrow = Mt + (mc + k) * 64 + ad0;
                #pragma unroll
                for (int jj = 0; jj < 4; jj++) {
                    const float4 m4 = *(const float4*)&mrow[jj * 4];
                    racc[jj * 4 + 0] = fmaf(wv, m4.x, racc[jj * 4 + 0]);
                    racc[jj * 4 + 1] = fmaf(wv, m4.y, racc[jj * 4 + 1]);
                    racc[jj * 4 + 2] = fmaf(wv, m4.z, racc[jj * 4 + 2]);
                    racc[jj * 4 + 3] = fmaf(wv, m4.w, racc[jj * 4 + 3]);
                }
            }
        }
        #pragma unroll
        for (int off = 32; off > 0; off >>= 1) wsum += __shfl_down(wsum, off);
        if (lane == 0) atomicAdd(&s_red[0], wsum);
    }
    __syncthreads();   // s_inj ready (s_inc ready since P0 barrier)

    // ---- P2: received = W@msg + inject(ports 0..3) + gated border(ports 8..11)
    #pragma unroll
    for (int j = 0; j < 16; j++) {
        const int d = ad0 + j;
        float v = racc[j];
        if (an < 4) v += s_inj[an * 64 + d];
        else if (an >= 8 && an < 12) v += s_inc[an - 8][d];
        s_in[an][d] = v;
    }
    __syncthreads();   // s_in = [received | h] complete

    // Wave-level mappings for the two MLPs:
    //   layer1: wave w owns hidden cols [64w,64w+64); lane: hh0 = 64w+4*(l&15),
    //           n = (l>>4) + 4j, j=0..15  (4 hh x 16 n per lane)
    //   layer2: lane: d0 = l&31, d1 = d0+32, n = 8*(2w + (l>>5)) + j, j=0..7
    const int hh0   = (w << 6) + ((lane & 15) << 2);
    const int nbase = lane >> 4;
    const int d0 = lane & 31, d1 = d0 + 32;
    const int n0 = ((w << 1) + (lane >> 5)) << 3;

    // ---- P3: state layer1  hid = tanh((in @ w1^T + b1)*gs1 + gb1)
    {
        float acc0[16], acc1[16], acc2[16], acc3[16];
        #pragma unroll
        for (int j = 0; j < 16; j++) { acc0[j]=0.f; acc1[j]=0.f; acc2[j]=0.f; acc3[j]=0.f; }
        for (int f = 0; f < 128; f += 4) {
            const float4 wa = *(const float4*)&sw1[(hh0 + 0) * 128 + f];
            const float4 wb = *(const float4*)&sw1[(hh0 + 1) * 128 + f];
            const float4 wc = *(const float4*)&sw1[(hh0 + 2) * 128 + f];
            const float4 wd = *(const float4*)&sw1[(hh0 + 3) * 128 + f];
            #pragma unroll
            for (int j = 0; j < 16; j++) {
                const float4 x4 = *(const float4*)&s_in[nbase + 4 * j][f];
                fma4(acc0[j], wa, x4);
                fma4(acc1[j], wb, x4);
                fma4(acc2[j], wc, x4);
                fma4(acc3[j], wd, x4);
            }
        }
        const float4 b1v  = *(const float4*)&sb1[hh0];
        const float4 gs1v = *(const float4*)&sgs1[g * HSZ + hh0];
        const float4 gb1v = *(const float4*)&sgb1[g * HSZ + hh0];
        #pragma unroll
        for (int j = 0; j < 16; j++) {
            float4 o;
            o.x = fast_tanh(fmaf(acc0[j] + b1v.x, gs1v.x, gb1v.x));
            o.y = fast_tanh(fmaf(acc1[j] + b1v.y, gs1v.y, gb1v.y));
            o.z = fast_tanh(fmaf(acc2[j] + b1v.z, gs1v.z, gb1v.z));
            o.w = fast_tanh(fmaf(acc3[j] + b1v.w, gs1v.w, gb1v.w));
            *(float4*)&s_hid[nbase + 4 * j][hh0] = o;
        }
    }
    __syncthreads();

    // ---- P4: state layer2 -> cand -> h_new (global + s_in[:,0:64] + h_mean)
    {
        float accA[8], accB[8];
        #pragma unroll
        for (int j = 0; j < 8; j++) { accA[j] = 0.f; accB[j] = 0.f; }
        for (int hc = 0; hc < 256; hc += 4) {
            const float4 wa = *(const float4*)&sw2[d0 * 256 + hc];
            const float4 wb = *(const float4*)&sw2[d1 * 256 + hc];
            #pragma unroll
            for (int j = 0; j < 8; j++) {
                const float4 x4 = *(const float4*)&s_hid[n0 + j][hc];
                fma4(accA[j], wa, x4);
                fma4(accB[j], wb, x4);
            }
        }
        const float bA  = sb2[d0],            bB  = sb2[d1];
        const float gsA = sgs2[g * 64 + d0],  gsB = sgs2[g * 64 + d1];
        const float gbA = sgb2[g * 64 + d0],  gbB = sgb2[g * 64 + d1];
        float hsA = 0.f, hsB = 0.f;
        #pragma unroll
        for (int j = 0; j < 8; j++) {
            const int n = n0 + j;
            const float dec = fast_sigmoid(decayp[(size_t)bc * 64 + n]);
            const float cA = fast_tanh(fmaf(accA[j] + bA, gsA, gbA));
            const float cB = fast_tanh(fmaf(accB[j] + bB, gsB, gbB));
            const float hA = fmaf(dec, s_in[n][64 + d0] - cA, cA); // dec*h + (1-dec)*c
            const float hB = fmaf(dec, s_in[n][64 + d1] - cB, cB);
            out_h[tile + n * 64 + d0] = hA;
            out_h[tile + n * 64 + d1] = hB;
            s_in[n][d0] = hA;
            s_in[n][d1] = hB;
            hsA += hA; hsB += hB;
        }
        atomicAdd(&s_hmean[d0], hsA);
        atomicAdd(&s_hmean[d1], hsB);
    }
    __syncthreads();

    // ---- P5: msg layer1 (input = h_new in s_in[:,0:64])
    {
        float acc0[16], acc1[16], acc2[16], acc3[16];
        #pragma unroll
        for (int j = 0; j < 16; j++) { acc0[j]=0.f; acc1[j]=0.f; acc2[j]=0.f; acc3[j]=0.f; }
        for (int f = 0; f < 64; f += 4) {
            const float4 wa = *(const float4*)&mw1[(hh0 + 0) * 64 + f];
            const float4 wb = *(const float4*)&mw1[(hh0 + 1) * 64 + f];
            const float4 wc = *(const float4*)&mw1[(hh0 + 2) * 64 + f];
            const float4 wd = *(const float4*)&mw1[(hh0 + 3) * 64 + f];
            #pragma unroll
            for (int j = 0; j < 16; j++) {
                const float4 x4 = *(const float4*)&s_in[nbase + 4 * j][f];
                fma4(acc0[j], wa, x4);
                fma4(acc1[j], wb, x4);
                fma4(acc2[j], wc, x4);
                fma4(acc3[j], wd, x4);
            }
        }
        const float4 b1v  = *(const float4*)&mb1[hh0];
        const float4 gs1v = *(const float4*)&mgs1[g * HSZ + hh0];
        const float4 gb1v = *(const float4*)&mgb1[g * HSZ + hh0];
        #pragma unroll
        for (int j = 0; j < 16; j++) {
            float4 o;
            o.x = fast_tanh(fmaf(acc0[j] + b1v.x, gs1v.x, gb1v.x));
            o.y = fast_tanh(fmaf(acc1[j] + b1v.y, gs1v.y, gb1v.y));
            o.z = fast_tanh(fmaf(acc2[j] + b1v.z, gs1v.z, gb1v.z));
            o.w = fast_tanh(fmaf(acc3[j] + b1v.w, gs1v.w, gb1v.w));
            *(float4*)&s_hid[nbase + 4 * j][hh0] = o;
        }
    }
    __syncthreads();

    // ---- P6: msg layer2 -> msg_new (+neuron_id), msg_mean, readout
    {
        float accA[8], accB[8];
        #pragma unroll
        for (int j = 0; j < 8; j++) { accA[j] = 0.f; accB[j] = 0.f; }
        for (int hc = 0; hc < 256; hc += 4) {
            const float4 wa = *(const float4*)&mw2[d0 * 256 + hc];
            const float4 wb = *(const float4*)&mw2[d1 * 256 + hc];
            #pragma unroll
            for (int j = 0; j < 8; j++) {
                const float4 x4 = *(const float4*)&s_hid[n0 + j][hc];
                fma4(accA[j], wa, x4);
                fma4(accB[j], wb, x4);
            }
        }
        const float bA  = mb2[d0],            bB  = mb2[d1];
        const float gsA = mgs2[g * 64 + d0],  gsB = mgs2[g * 64 + d1];
        const float gbA = mgb2[g * 64 + d0],  gbB = mgb2[g * 64 + d1];
        float msA = 0.f, msB = 0.f, roA = 0.f, roB = 0.f;
        #pragma unroll
        for (int j = 0; j < 8; j++) {
            const int n = n0 + j;
            const float mA = fast_tanh(fmaf(accA[j] + bA, gsA, gbA))
                             + nidp[(size_t)c * 4096 + n * 64 + d0];
            const float mB = fast_tanh(fmaf(accB[j] + bB, gsB, gbB))
                             + nidp[(size_t)c * 4096 + n * 64 + d1];
            out_msg[tile + n * 64 + d0] = mA;
            out_msg[tile + n * 64 + d1] = mB;
            msA += mA; msB += mB;
            if (n >= 4 && n < 8) { roA += mA; roB += mB; }
        }
        atomicAdd(&s_mmean[d0], msA);
        atomicAdd(&s_mmean[d1], msB);
        if (n0 == 0) {   // this lane's n-range is 0..7 (contains ports 4..7)
            out_read[((size_t)b * NCC + c) * 64 + d0] = 0.5f * roA;
            out_read[((size_t)b * NCC + c) * 64 + d1] = 0.5f * roB;
        }
    }
    __syncthreads();

    // ---- P7: feats = [h_mean(64) | msg_mean(64) | W_row | decay_mean | ctx(64) | bgl(4)]
    if (t < MODIN) {
        float v;
        if (t < 64)        v = s_hmean[t] * (1.f / 64.f);
        else if (t < 128)  v = s_mmean[t - 64] * (1.f / 64.f);
        else if (t == 128) v = s_red[0] * (1.f / 16384.f);   // sum|W| counted 4x / (4*64*64)
        else if (t == 129) v = s_red[1] * (1.f / 64.f);
        else if (t < 194)  v = ctxp[(size_t)bc * 64 + (t - 130)];
        else               v = bglp[(size_t)bc * 4 + (t - 194)];
        feats[(size_t)bc * MODIN + t] = v;
    }
}

// ---------------------------------------------------------------------------
// Kernel 2: per-cell modulation MLP (distinct weights per cell).
//   block = 256 threads, grid = NC = 1024; processes all 8 batch rows.
// ---------------------------------------------------------------------------
__global__ __launch_bounds__(256, 2)
void mg_mod_kernel(
    const float* __restrict__ feats, const float* __restrict__ modw1,
    const float* __restrict__ modb1, const float* __restrict__ modw2,
    const float* __restrict__ modb2, const float* __restrict__ ctxp,
    const float* __restrict__ bglp,  float* __restrict__ out_ctx,
    float* __restrict__ out_bg)
{
    const int c = blockIdx.x;
    const int t = threadIdx.x;
    __shared__ float s_f[8][MODIN];
    __shared__ float s_h2[8][HMODL];

    for (int k = t; k < 8 * MODIN; k += 256) {
        const int b = k / MODIN, f = k - b * MODIN;
        s_f[b][f] = feats[((size_t)b * NCC + c) * MODIN + f];
    }
    __syncthreads();

    {
        const int hh = t & 127, bh = (t >> 7) * 4;
        float a0 = 0.f, a1 = 0.f, a2 = 0.f, a3 = 0.f;
        const float* wp = modw1 + (size_t)c * MODIN * HMODL + hh;
        for (int f = 0; f < MODIN; f++) {
            const float wv = wp[(size_t)f * HMODL];
            a0 = fmaf(s_f[bh + 0][f], wv, a0);
            a1 = fmaf(s_f[bh + 1][f], wv, a1);
            a2 = fmaf(s_f[bh + 2][f], wv, a2);
            a3 = fmaf(s_f[bh + 3][f], wv, a3);
        }
        const float bv = modb1[(size_t)c * HMODL + hh];
        s_h2[bh + 0][hh] = fast_tanh(a0 + bv);
        s_h2[bh + 1][hh] = fast_tanh(a1 + bv);
        s_h2[bh + 2][hh] = fast_tanh(a2 + bv);
        s_h2[bh + 3][hh] = fast_tanh(a3 + bv);
    }
    __syncthreads();

    for (int idx = t; idx < 8 * MODOUT; idx += 256) {
        const int b = idx / MODOUT, o = idx - b * MODOUT;
        float acc = modb2[(size_t)c * MODOUT + o];
        const float* wp = modw2 + (size_t)c * HMODL * MODOUT + o;
        const float* hrow = s_h2[b];
        for (int hh = 0; hh < HMODL; hh++)
            acc = fmaf(hrow[hh], wp[(size_t)hh * MODOUT], acc);
        if (o < 64)
            out_ctx[((size_t)b * NCC + c) * 64 + o] =
                ctxp[((size_t)b * NCC + c) * 64 + o] + acc;
        else
            out_bg[((size_t)b * NCC + c) * 4 + (o - 64)] =
                bglp[((size_t)b * NCC + c) * 4 + (o - 64)] + acc;
    }
}

extern "C" void kernel_launch(void* const* d_in, const int* in_sizes, int n_in,
                              void* d_out, int out_size, void* d_ws, size_t ws_size,
                              hipStream_t stream) {
    const float* xp     = (const float*)d_in[0];
    const float* hp     = (const float*)d_in[1];
    const float* msgp   = (const float*)d_in[2];
    const float* Wp     = (const float*)d_in[3];
    const float* decayp = (const float*)d_in[4];
    const float* ctxp   = (const float*)d_in[5];
    const float* bglp   = (const float*)d_in[6];
    const float* nidp   = (const float*)d_in[7];
    const float* sw1    = (const float*)d_in[8];
    const float* sb1    = (const float*)d_in[9];
    const float* sgs1   = (const float*)d_in[10];
    const float* sgb1   = (const float*)d_in[11];
    const float* sw2    = (const float*)d_in[12];
    const float* sb2    = (const float*)d_in[13];
    const float* sgs2   = (const float*)d_in[14];
    const float* sgb2   = (const float*)d_in[15];
    const float* mw1    = (const float*)d_in[16];
    const float* mb1    = (const float*)d_in[17];
    const float* mgs1   = (const float*)d_in[18];
    const float* mgb1   = (const float*)d_in[19];
    const float* mw2    = (const float*)d_in[20];
    const float* mb2    = (const float*)d_in[21];
    const float* mgs2   = (const float*)d_in[22];
    const float* mgb2   = (const float*)d_in[23];
    const float* iw     = (const float*)d_in[24];
    const float* ibias  = (const float*)d_in[25];
    const float* modw1  = (const float*)d_in[26];
    const float* modb1  = (const float*)d_in[27];
    const float* modw2  = (const float*)d_in[28];
    const float* modb2  = (const float*)d_in[29];
    const int*   c2g    = (const int*)d_in[30];

    float* out       = (float*)d_out;
    float* out_read  = out;                         // 8*1024*64      = 524288
    float* out_h     = out_read + 524288;           // 8*1024*64*64   = 33554432
    float* out_msg   = out_h + 33554432;
    float* out_ctx   = out_msg + 33554432;          // 524288
    float* out_bg    = out_ctx + 524288;            // 32768
    float* feats     = (float*)d_ws;                // 8*1024*198 floats = 6.5 MB

    mg_cell_kernel<<<8192, 256, 0, stream>>>(
        xp, hp, msgp, Wp, decayp, ctxp, bglp, nidp,
        sw1, sb1, sgs1, sgb1, sw2, sb2, sgs2, sgb2,
        mw1, mb1, mgs1, mgb1, mw2, mb2, mgs2, mgb2,
        iw, ibias, c2g, out_read, out_h, out_msg, feats);

    mg_mod_kernel<<<1024, 256, 0, stream>>>(
        feats, modw1, modb1, modw2, modb2, ctxp, bglp, out_ctx, out_bg);
}

// Round 2
// 851.928 us; speedup vs baseline: 3.1231x; 3.1231x over previous
//
#include <hip/hip_runtime.h>

#define NCC 1024
#define MODIN 198
#define MODOUT 68
#define HMODL 128

typedef __attribute__((ext_vector_type(8))) short s8v;   // 8 bf16 = 4 VGPR
typedef __attribute__((ext_vector_type(4))) float f4v;   // MFMA acc
typedef unsigned short ushort_t;
typedef unsigned int uint_t;

// ws layout (ushort elems): sw1 @0 (32768), sw2 @32768 (16384), mw1 @49152 (16384), mw2 @65536 (16384)
#define OFF_SW1 0
#define OFF_SW2 32768
#define OFF_MW1 49152
#define OFF_MW2 65536
#define FEATS_BYTE_OFF 262144   // feats: 8192 cells x 132 f32

__device__ __forceinline__ float fast_tanh(float x) {
    x = fminf(15.f, fmaxf(-15.f, x));
    float e = __expf(2.f * x);
    return (e - 1.f) / (e + 1.f);
}
__device__ __forceinline__ float fast_sigmoid(float x) {
    x = fminf(30.f, fmaxf(-30.f, x));
    return 1.f / (1.f + __expf(-x));
}
__device__ __forceinline__ ushort_t f2bf(float x) {   // RNE f32->bf16
    uint_t u = __builtin_bit_cast(uint_t, x);
    u += 0x7FFFu + ((u >> 16) & 1u);
    return (ushort_t)(u >> 16);
}
__device__ __forceinline__ uint_t pk2(float a, float b) {
    return (uint_t)f2bf(a) | ((uint_t)f2bf(b) << 16);
}
// XOR swizzle on LDS byte offsets: spreads row-major 16B frag reads across 8 slots
#define SWZ(byteoff, row) ((byteoff) ^ (((row) & 7) << 4))

// ---------------------------------------------------------------------------
// Kernel 0: convert the 4 shared MLP weight matrices to bf16 once per launch
// ---------------------------------------------------------------------------
__global__ __launch_bounds__(256)
void mg_cvtw(const float* __restrict__ sw1, const float* __restrict__ sw2,
             const float* __restrict__ mw1, const float* __restrict__ mw2,
             ushort_t* __restrict__ o) {
    const int i = blockIdx.x * 256 + threadIdx.x;   // grid 320 -> 81920 exact
    float v;
    if (i < 32768)      v = sw1[i];
    else if (i < 49152) v = sw2[i - 32768];
    else if (i < 65536) v = mw1[i - 49152];
    else                v = mw2[i - 65536];
    o[i] = f2bf(v);
}

// ---------------------------------------------------------------------------
// Kernel 1: per (b, cell) block; stages 1-6 + feats, MFMA matmuls.
// 256 threads = 4 waves. Wave decompositions use mfma_f32_16x16x32_bf16:
//   A-frag: row = lane&15 (in 16-tile), k = (lane>>4)*8 + j (contiguous)
//   B-frag (B^T stored [N][K]): col = lane&15, k contiguous
//   D: col = lane&15, row = (lane>>4)*4 + reg   [m89-verified]
// ---------------------------------------------------------------------------
__global__ __launch_bounds__(256, 3)
void mg_cell_kernel(
    const float* __restrict__ xp,   const float* __restrict__ hp,
    const float* __restrict__ msgp, const float* __restrict__ Wp,
    const float* __restrict__ decayp, const float* __restrict__ ctxp,
    const float* __restrict__ bglp, const float* __restrict__ nidp,
    const float* __restrict__ sb1,  const float* __restrict__ sgs1,
    const float* __restrict__ sgb1, const float* __restrict__ sb2,
    const float* __restrict__ sgs2, const float* __restrict__ sgb2,
    const float* __restrict__ mb1,  const float* __restrict__ mgs1,
    const float* __restrict__ mgb1, const float* __restrict__ mb2,
    const float* __restrict__ mgs2, const float* __restrict__ mgb2,
    const float* __restrict__ iw,   const float* __restrict__ ibias,
    const int*   __restrict__ c2g,  const ushort_t* __restrict__ wb,
    float* __restrict__ out_read, float* __restrict__ out_h,
    float* __restrict__ out_msg,  float* __restrict__ wsf)
{
    const int t  = threadIdx.x;
    const int bc = blockIdx.x;
    const int b  = bc >> 10, c = bc & 1023;
    const int gh = c >> 5, gwc = c & 31;
    const int lane = t & 63, w = t >> 6;
    const int cl = lane & 15, q = lane >> 4;
    const int g  = c2g[c];
    const size_t tile = (size_t)bc * 4096;

    // LDS: sHid [64][256] bf16 (32KB) overlays sW [64][64] + sMsgT [64][64]
    __shared__ ushort_t sHid[16384];
    __shared__ ushort_t sIn[8192];     // [64][128] bf16: [received | h]
    __shared__ float s_x[64];
    __shared__ float s_inj[256];
    __shared__ float s_inc[4][64];
    __shared__ float s_dec[64];
    __shared__ float s_hmean[64];
    __shared__ float s_mmean[64];
    __shared__ float s_wsum[4];
    __shared__ float s_dsum;

    ushort_t* sW    = sHid;            // [64][64], byte stride 128
    ushort_t* sMsgT = sHid + 4096;     // [64][64] (row = d, col = m)

    // ================= P0: staging =================
    // W -> sW bf16 (+ sum|W|)
    {
        const int n = t >> 2, m0 = (t & 3) * 16;
        const float* src = Wp + tile + n * 64 + m0;
        float wsum = 0.f;
        #pragma unroll
        for (int i = 0; i < 4; i++) {
            const float4 v = *(const float4*)(src + i * 4);
            wsum += fabsf(v.x) + fabsf(v.y) + fabsf(v.z) + fabsf(v.w);
            const int m = m0 + i * 4;
            *(uint_t*)((char*)sW + SWZ(n * 128 + m * 2, n))       = pk2(v.x, v.y);
            *(uint_t*)((char*)sW + SWZ(n * 128 + (m + 2) * 2, n)) = pk2(v.z, v.w);
        }
        #pragma unroll
        for (int off = 32; off > 0; off >>= 1) wsum += __shfl_down(wsum, off);
        if (lane == 0) s_wsum[w] = wsum;
    }
    // msg^T -> sMsgT bf16
    {
        const int mr = t >> 4, d0 = (t & 15) * 4;
        #pragma unroll
        for (int i = 0; i < 4; i++) {
            const int m = mr + i * 16;
            const float4 v = *(const float4*)(msgp + tile + (size_t)m * 64 + d0);
            *(ushort_t*)((char*)sMsgT + SWZ((d0 + 0) * 128 + m * 2, d0 + 0)) = f2bf(v.x);
            *(ushort_t*)((char*)sMsgT + SWZ((d0 + 1) * 128 + m * 2, d0 + 1)) = f2bf(v.y);
            *(ushort_t*)((char*)sMsgT + SWZ((d0 + 2) * 128 + m * 2, d0 + 2)) = f2bf(v.z);
            *(ushort_t*)((char*)sMsgT + SWZ((d0 + 3) * 128 + m * 2, d0 + 3)) = f2bf(v.w);
        }
    }
    // h -> sIn[:,64:128] bf16
    {
        const int d0 = (t & 15) * 4;
        #pragma unroll
        for (int i = 0; i < 4; i++) {
            const int n = (t >> 4) + i * 16;
            const float4 v = *(const float4*)(hp + tile + (size_t)n * 64 + d0);
            *(uint_t*)((char*)sIn + SWZ(n * 256 + (64 + d0) * 2, n))     = pk2(v.x, v.y);
            *(uint_t*)((char*)sIn + SWZ(n * 256 + (64 + d0 + 2) * 2, n)) = pk2(v.z, v.w);
        }
    }
    if (t < 16)
        *(float4*)&s_x[t * 4] = *(const float4*)&xp[((size_t)b * NCC + c) * 64 + t * 4];
    // gated border incoming (wave p handles port p)
    {
        const int p = w, d = lane;
        int ok, nc2, qq;
        if      (p == 0) { ok = (gh > 0);   nc2 = c - 32; qq = 1; }
        else if (p == 1) { ok = (gh < 31);  nc2 = c + 32; qq = 0; }
        else if (p == 2) { ok = (gwc > 0);  nc2 = c - 1;  qq = 3; }
        else             { ok = (gwc < 31); nc2 = c + 1;  qq = 2; }
        float v = 0.f;
        if (ok) v = msgp[((size_t)b * NCC + nc2) * 4096 + (8 + qq) * 64 + d];
        s_inc[p][d] = fast_sigmoid(bglp[(size_t)bc * 4 + p]) * v;
    }
    if (w == 0) {   // decay: sigmoid table + logit sum
        const float dl = decayp[(size_t)bc * 64 + lane];
        s_dec[lane] = fast_sigmoid(dl);
        float v = dl;
        #pragma unroll
        for (int off = 32; off > 0; off >>= 1) v += __shfl_down(v, off);
        if (lane == 0) s_dsum = v;
    }
    __syncthreads();

    // ================= P1: inject (VALU) + W@msg (MFMA) =================
    {
        const float* wrow = iw + (size_t)g * 16384 + t * 64;
        float acc = ibias[g * 256 + t];
        for (int i = 0; i < 64; i += 4) {
            const float4 w4 = *(const float4*)(wrow + i);
            acc = fmaf(w4.x, s_x[i + 0], acc);
            acc = fmaf(w4.y, s_x[i + 1], acc);
            acc = fmaf(w4.z, s_x[i + 2], acc);
            acc = fmaf(w4.w, s_x[i + 3], acc);
        }
        s_inj[t] = acc;
    }
    const f4v fzero = {0.f, 0.f, 0.f, 0.f};
    f4v wm[4] = {fzero, fzero, fzero, fzero};
    {
        #pragma unroll
        for (int ks = 0; ks < 2; ks++) {
            const int k0 = ks * 32 + q * 8;
            const int brow = 16 * w + cl;
            const s8v bf = *(const s8v*)((const char*)sMsgT + SWZ(brow * 128 + k0 * 2, brow));
            #pragma unroll
            for (int rt = 0; rt < 4; rt++) {
                const int ar = rt * 16 + cl;
                const s8v af = *(const s8v*)((const char*)sW + SWZ(ar * 128 + k0 * 2, ar));
                wm[rt] = __builtin_amdgcn_mfma_f32_16x16x32_bf16(af, bf, wm[rt], 0, 0, 0);
            }
        }
    }
    __syncthreads();

    // ================= P2: received(+inject+border) -> sIn[:,0:64] =================
    {
        const int d = 16 * w + cl;
        #pragma unroll
        for (int rt = 0; rt < 4; rt++)
            #pragma unroll
            for (int r = 0; r < 4; r++) {
                const int n = rt * 16 + q * 4 + r;
                float v = wm[rt][r];
                if (n < 4)                 v += s_inj[n * 64 + d];
                else if (n >= 8 && n < 12) v += s_inc[n - 8][d];
                *(ushort_t*)((char*)sIn + SWZ(n * 256 + d * 2, n)) = f2bf(v);
            }
    }
    __syncthreads();

    // ================= P3: state L1 [64x128]@[128x256] -> sHid =================
    {
        f4v acc[4][4];
        #pragma unroll
        for (int i = 0; i < 4; i++)
            #pragma unroll
            for (int j = 0; j < 4; j++) acc[i][j] = fzero;
        const ushort_t* wb1 = wb + OFF_SW1;
        #pragma unroll
        for (int ks = 0; ks < 4; ks++) {
            const int k0 = ks * 32 + q * 8;
            s8v bfr[4], afr[4];
            #pragma unroll
            for (int ct = 0; ct < 4; ct++)
                bfr[ct] = *(const s8v*)(wb1 + (64 * w + ct * 16 + cl) * 128 + k0);
            #pragma unroll
            for (int rt = 0; rt < 4; rt++) {
                const int ar = rt * 16 + cl;
                afr[rt] = *(const s8v*)((const char*)sIn + SWZ(ar * 256 + k0 * 2, ar));
            }
            #pragma unroll
            for (int rt = 0; rt < 4; rt++)
                #pragma unroll
                for (int ct = 0; ct < 4; ct++)
                    acc[rt][ct] = __builtin_amdgcn_mfma_f32_16x16x32_bf16(afr[rt], bfr[ct], acc[rt][ct], 0, 0, 0);
        }
        #pragma unroll
        for (int ct = 0; ct < 4; ct++) {
            const int hcol = 64 * w + ct * 16 + cl;
            const float b1 = sb1[hcol], g1 = sgs1[g * 256 + hcol], o1 = sgb1[g * 256 + hcol];
            #pragma unroll
            for (int rt = 0; rt < 4; rt++)
                #pragma unroll
                for (int r = 0; r < 4; r++) {
                    const int n = rt * 16 + q * 4 + r;
                    const float vv = fast_tanh(fmaf(acc[rt][ct][r] + b1, g1, o1));
                    *(ushort_t*)((char*)sHid + SWZ(n * 512 + hcol * 2, n)) = f2bf(vv);
                }
        }
    }
    __syncthreads();

    // ================= P4: state L2 -> cand -> h_new =================
    {
        f4v a2[4] = {fzero, fzero, fzero, fzero};
        const ushort_t* wb2 = wb + OFF_SW2;
        const int d = 16 * w + cl;
        #pragma unroll
        for (int ks = 0; ks < 8; ks++) {
            const int k0 = ks * 32 + q * 8;
            const s8v bf = *(const s8v*)(wb2 + d * 256 + k0);
            #pragma unroll
            for (int rt = 0; rt < 4; rt++) {
                const int ar = rt * 16 + cl;
                const s8v af = *(const s8v*)((const char*)sHid + SWZ(ar * 512 + k0 * 2, ar));
                a2[rt] = __builtin_amdgcn_mfma_f32_16x16x32_bf16(af, bf, a2[rt], 0, 0, 0);
            }
        }
        const float b2 = sb2[d], g2 = sgs2[g * 64 + d], o2 = sgb2[g * 64 + d];
        float hsum = 0.f;
        #pragma unroll
        for (int rt = 0; rt < 4; rt++)
            #pragma unroll
            for (int r = 0; r < 4; r++) {
                const int n = rt * 16 + q * 4 + r;
                const float cand = fast_tanh(fmaf(a2[rt][r] + b2, g2, o2));
                const float hv  = hp[tile + (size_t)n * 64 + d];
                const float dec = s_dec[n];
                const float hn  = fmaf(dec, hv - cand, cand);
                out_h[tile + (size_t)n * 64 + d] = hn;
                *(ushort_t*)((char*)sIn + SWZ(n * 256 + d * 2, n)) = f2bf(hn);
                hsum += hn;
            }
        hsum += __shfl_xor(hsum, 16);
        hsum += __shfl_xor(hsum, 32);
        if (lane < 16) s_hmean[16 * w + lane] = hsum;
    }
    __syncthreads();

    // ================= P5: msg L1 [64x64]@[64x256] -> sHid =================
    {
        f4v acc[4][4];
        #pragma unroll
        for (int i = 0; i < 4; i++)
            #pragma unroll
            for (int j = 0; j < 4; j++) acc[i][j] = fzero;
        const ushort_t* wb1 = wb + OFF_MW1;
        #pragma unroll
        for (int ks = 0; ks < 2; ks++) {
            const int k0 = ks * 32 + q * 8;
            s8v bfr[4], afr[4];
            #pragma unroll
            for (int ct = 0; ct < 4; ct++)
                bfr[ct] = *(const s8v*)(wb1 + (64 * w + ct * 16 + cl) * 64 + k0);
            #pragma unroll
            for (int rt = 0; rt < 4; rt++) {
                const int ar = rt * 16 + cl;
                afr[rt] = *(const s8v*)((const char*)sIn + SWZ(ar * 256 + k0 * 2, ar));
            }
            #pragma unroll
            for (int rt = 0; rt < 4; rt++)
                #pragma unroll
                for (int ct = 0; ct < 4; ct++)
                    acc[rt][ct] = __builtin_amdgcn_mfma_f32_16x16x32_bf16(afr[rt], bfr[ct], acc[rt][ct], 0, 0, 0);
        }
        #pragma unroll
        for (int ct = 0; ct < 4; ct++) {
            const int hcol = 64 * w + ct * 16 + cl;
            const float b1 = mb1[hcol], g1 = mgs1[g * 256 + hcol], o1 = mgb1[g * 256 + hcol];
            #pragma unroll
            for (int rt = 0; rt < 4; rt++)
                #pragma unroll
                for (int r = 0; r < 4; r++) {
                    const int n = rt * 16 + q * 4 + r;
                    const float vv = fast_tanh(fmaf(acc[rt][ct][r] + b1, g1, o1));
                    *(ushort_t*)((char*)sHid + SWZ(n * 512 + hcol * 2, n)) = f2bf(vv);
                }
        }
    }
    __syncthreads();

    // ================= P6: msg L2 -> msg_new, means, readout =================
    {
        f4v a2[4] = {fzero, fzero, fzero, fzero};
        const ushort_t* wb2 = wb + OFF_MW2;
        const int d = 16 * w + cl;
        #pragma unroll
        for (int ks = 0; ks < 8; ks++) {
            const int k0 = ks * 32 + q * 8;
            const s8v bf = *(const s8v*)(wb2 + d * 256 + k0);
            #pragma unroll
            for (int rt = 0; rt < 4; rt++) {
                const int ar = rt * 16 + cl;
                const s8v af = *(const s8v*)((const char*)sHid + SWZ(ar * 512 + k0 * 2, ar));
                a2[rt] = __builtin_amdgcn_mfma_f32_16x16x32_bf16(af, bf, a2[rt], 0, 0, 0);
            }
        }
        const float b2 = mb2[d], g2 = mgs2[g * 64 + d], o2 = mgb2[g * 64 + d];
        float msum = 0.f, ro = 0.f;
        #pragma unroll
        for (int rt = 0; rt < 4; rt++)
            #pragma unroll
            for (int r = 0; r < 4; r++) {
                const int n = rt * 16 + q * 4 + r;
                const float mv = fast_tanh(fmaf(a2[rt][r] + b2, g2, o2))
                                 + nidp[(size_t)c * 4096 + (size_t)n * 64 + d];
                out_msg[tile + (size_t)n * 64 + d] = mv;
                msum += mv;
                if (rt == 0 && q == 1) ro += mv;   // n = 4..7
            }
        msum += __shfl_xor(msum, 16);
        msum += __shfl_xor(msum, 32);
        if (lane < 16) s_mmean[16 * w + lane] = msum;
        if (q == 1) out_read[((size_t)b * NCC + c) * 64 + d] = ro * 0.5f;
    }
    __syncthreads();

    // ================= P7: feats record (130 values) =================
    if (t < 132) {
        float v = 0.f;
        if (t < 64)        v = s_hmean[t] * (1.f / 64.f);
        else if (t < 128)  v = s_mmean[t - 64] * (1.f / 64.f);
        else if (t == 128) v = (s_wsum[0] + s_wsum[1] + s_wsum[2] + s_wsum[3]) * (1.f / 4096.f);
        else if (t == 129) v = s_dsum * (1.f / 64.f);
        wsf[(size_t)bc * 132 + t] = v;
    }
}

// ---------------------------------------------------------------------------
// Kernel 2: per-cell modulation MLP (distinct weights per cell)
// ---------------------------------------------------------------------------
__global__ __launch_bounds__(256, 2)
void mg_mod_kernel(
    const float* __restrict__ wsf,   const float* __restrict__ modw1,
    const float* __restrict__ modb1, const float* __restrict__ modw2,
    const float* __restrict__ modb2, const float* __restrict__ ctxp,
    const float* __restrict__ bglp,  float* __restrict__ out_ctx,
    float* __restrict__ out_bg)
{
    const int c = blockIdx.x;
    const int t = threadIdx.x;
    __shared__ float s_f[8][MODIN];
    __shared__ float s_h2[8][HMODL];

    for (int k = t; k < 8 * MODIN; k += 256) {
        const int b = k / MODIN, f = k - b * MODIN;
        float v;
        if (f < 130)      v = wsf[((size_t)b * NCC + c) * 132 + f];
        else if (f < 194) v = ctxp[((size_t)b * NCC + c) * 64 + (f - 130)];
        else              v = bglp[((size_t)b * NCC + c) * 4 + (f - 194)];
        s_f[b][f] = v;
    }
    __syncthreads();

    {
        const int hh = t & 127, bh = (t >> 7) * 4;
        float a0 = 0.f, a1 = 0.f, a2 = 0.f, a3 = 0.f;
        const float* wp = modw1 + (size_t)c * MODIN * HMODL + hh;
        for (int f = 0; f < MODIN; f++) {
            const float wv = wp[(size_t)f * HMODL];
            a0 = fmaf(s_f[bh + 0][f], wv, a0);
            a1 = fmaf(s_f[bh + 1][f], wv, a1);
            a2 = fmaf(s_f[bh + 2][f], wv, a2);
            a3 = fmaf(s_f[bh + 3][f], wv, a3);
        }
        const float bv = modb1[(size_t)c * HMODL + hh];
        s_h2[bh + 0][hh] = fast_tanh(a0 + bv);
        s_h2[bh + 1][hh] = fast_tanh(a1 + bv);
        s_h2[bh + 2][hh] = fast_tanh(a2 + bv);
        s_h2[bh + 3][hh] = fast_tanh(a3 + bv);
    }
    __syncthreads();

    for (int idx = t; idx < 8 * MODOUT; idx += 256) {
        const int b = idx / MODOUT, o = idx - b * MODOUT;
        float acc = modb2[(size_t)c * MODOUT + o];
        const float* wp = modw2 + (size_t)c * HMODL * MODOUT + o;
        const float* hrow = s_h2[b];
        for (int hh = 0; hh < HMODL; hh++)
            acc = fmaf(hrow[hh], wp[(size_t)hh * MODOUT], acc);
        if (o < 64)
            out_ctx[((size_t)b * NCC + c) * 64 + o] =
                ctxp[((size_t)b * NCC + c) * 64 + o] + acc;
        else
            out_bg[((size_t)b * NCC + c) * 4 + (o - 64)] =
                bglp[((size_t)b * NCC + c) * 4 + (o - 64)] + acc;
    }
}

extern "C" void kernel_launch(void* const* d_in, const int* in_sizes, int n_in,
                              void* d_out, int out_size, void* d_ws, size_t ws_size,
                              hipStream_t stream) {
    const float* xp     = (const float*)d_in[0];
    const float* hp     = (const float*)d_in[1];
    const float* msgp   = (const float*)d_in[2];
    const float* Wp     = (const float*)d_in[3];
    const float* decayp = (const float*)d_in[4];
    const float* ctxp   = (const float*)d_in[5];
    const float* bglp   = (const float*)d_in[6];
    const float* nidp   = (const float*)d_in[7];
    const float* sw1    = (const float*)d_in[8];
    const float* sb1    = (const float*)d_in[9];
    const float* sgs1   = (const float*)d_in[10];
    const float* sgb1   = (const float*)d_in[11];
    const float* sw2    = (const float*)d_in[12];
    const float* sb2    = (const float*)d_in[13];
    const float* sgs2   = (const float*)d_in[14];
    const float* sgb2   = (const float*)d_in[15];
    const float* mw1    = (const float*)d_in[16];
    const float* mb1    = (const float*)d_in[17];
    const float* mgs1   = (const float*)d_in[18];
    const float* mgb1   = (const float*)d_in[19];
    const float* mw2    = (const float*)d_in[20];
    const float* mb2    = (const float*)d_in[21];
    const float* mgs2   = (const float*)d_in[22];
    const float* mgb2   = (const float*)d_in[23];
    const float* iw     = (const float*)d_in[24];
    const float* ibias  = (const float*)d_in[25];
    const float* modw1  = (const float*)d_in[26];
    const float* modb1  = (const float*)d_in[27];
    const float* modw2  = (const float*)d_in[28];
    const float* modb2  = (const float*)d_in[29];
    const int*   c2g    = (const int*)d_in[30];

    float* out      = (float*)d_out;
    float* out_read = out;                 // 524288
    float* out_h    = out_read + 524288;   // 33554432
    float* out_msg  = out_h + 33554432;    // 33554432
    float* out_ctx  = out_msg + 33554432;  // 524288
    float* out_bg   = out_ctx + 524288;    // 32768

    ushort_t* wb  = (ushort_t*)d_ws;                          // 160KB bf16 weights
    float*    wsf = (float*)((char*)d_ws + FEATS_BYTE_OFF);   // 8192 x 132 f32

    mg_cvtw<<<320, 256, 0, stream>>>(sw1, sw2, mw1, mw2, wb);

    mg_cell_kernel<<<8192, 256, 0, stream>>>(
        xp, hp, msgp, Wp, decayp, ctxp, bglp, nidp,
        sb1, sgs1, sgb1, sb2, sgs2, sgb2,
        mb1, mgs1, mgb1, mb2, mgs2, mgb2,
        iw, ibias, c2g, wb, out_read, out_h, out_msg, wsf);

    mg_mod_kernel<<<1024, 256, 0, stream>>>(
        wsf, modw1, modb1, modw2, modb2, ctxp, bglp, out_ctx, out_bg);
}